// Round 30
// baseline (10013.248 us; speedup 1.0000x reference)
//
#include <hip/hip_runtime.h>

// Farthest point sampling, B=32, N=32768, npoint=4096.
// R30 = R29's xy-LDS-cache idea, implemented CONFLICT-FREE:
//  - R29's float4 xy_lds reads were 16B/lane = 8-way bank conflict
//    (4.9e7 counted) and ate the 256->224KB/step stream cut.
//  - Now: separate xc[4096]/yc[4096] float arrays in the SAME pair layout
//    as pz (idx = (c-14)*2048 + 2*tid + j); reads are two ds_read_b64
//    (8B/lane -> 2-way aliasing = free). Chunk 14 fully cached; chunk 15
//    cached for tid<992 (half of wave 15 diverges to L2 tail).
//  - LDS budget EXACT: 131072(pz) + 16384(xc) + 16384(yc) = 163,840B
//    = cap. Reduce slots alias into xc's never-written tail rows
//    (cached rows end at 4031; s_val/s_idx live at float idx 4032+).
// Everything else byte-identical to R26 (8.06ms proven): value-only inner
// loop, DPP wave max (lane63) -> 32-bit LDS atomicMax -> B1 -> phase-B
// constant-index rescan (candidates only) -> atomicMin -> B2 -> 3-slot
// rotation reset; centroid xy from ws (L2 broadcast), z from LDS; ws xy
// pack kernel. First-occurrence argmax preserved. PASSING arithmetic
// (R6, bit-exact): d = fmaf(dz,dz, fmaf(dx,dx, dy*dy)), contract(off),
// fminf chain. Output float32: [B*NPOINT] idx, [B*NPOINT*3] coords.

#define BATCH  32
#define NPTS   32768
#define NPOINT 4096
#define NT     1024
#define NCH    16            // chunks of 2: 32 points per thread
#define WS_NEEDED ((size_t)BATCH * NPTS * 8)   // float2 xy per point = 8MB

#define DPP1(x, ctrl, rm) __builtin_amdgcn_update_dpp((x), (x), (ctrl), (rm), 0xf, false)

__device__ __forceinline__ float wave_max_dpp(float v) {
    unsigned int u = __float_as_uint(v);
    u = __float_as_uint(fmaxf(__uint_as_float(u), __uint_as_float(DPP1(u, 0xB1, 0xf))));
    u = __float_as_uint(fmaxf(__uint_as_float(u), __uint_as_float(DPP1(u, 0x4E, 0xf))));
    u = __float_as_uint(fmaxf(__uint_as_float(u), __uint_as_float(DPP1(u, 0x141, 0xf))));
    u = __float_as_uint(fmaxf(__uint_as_float(u), __uint_as_float(DPP1(u, 0x140, 0xf))));
    u = __float_as_uint(fmaxf(__uint_as_float(u), __uint_as_float(DPP1(u, 0x142, 0xa))));
    u = __float_as_uint(fmaxf(__uint_as_float(u), __uint_as_float(DPP1(u, 0x143, 0xc))));
    return __uint_as_float(u);   // lane 63 = wave max
}

// ---- prep: pack xy as float2[B][N] into ws (one-time, ~10us) ----
__global__ __launch_bounds__(256) void pack_xy(
    const float* __restrict__ xyz, float2* __restrict__ ws)
{
    const int i = blockIdx.x * 256 + threadIdx.x;   // 0 .. B*N-1
    ws[i] = make_float2(xyz[(size_t)i * 3 + 0], xyz[(size_t)i * 3 + 1]);
}

__global__ __launch_bounds__(NT, 1) void fps_kernel(
    const float* __restrict__ xyz,    // [B, N, 3] (setup only)
    const float2* __restrict__ wsxy,  // [B, N] packed xy
    float* __restrict__ out_idx,      // [B, NPOINT]
    float* __restrict__ out_xyz)      // [B, NPOINT, 3]
{
#pragma clang fp contract(off)
    __shared__ float pz_lds[NPTS];               // 128 KB
    __shared__ float xc_lds[4096];               // 16 KB (rows 4032+ = slots)
    __shared__ float yc_lds[4096];               // 16 KB   -> total 163,840B
    unsigned int* s_val = (unsigned int*)&xc_lds[4032];   // [3]
    int*          s_idx = (int*)&xc_lds[4040];            // [3]

    const int b   = blockIdx.x;
    const int tid = threadIdx.x;
    const float* base = xyz + (size_t)b * NPTS * 3;
    const float2* xy  = wsxy + (size_t)b * NPTS;
    const float4* xy4 = (const float4*)xy;       // 2 points per float4

    float dist[NCH * 2];
#pragma unroll
    for (int c = 0; c < NCH; ++c) {
        float xv[2], yv[2];
#pragma unroll
        for (int j = 0; j < 2; ++j) {
            const int g = c * 2048 + 2 * tid + j;
            xv[j] = base[g * 3 + 0];
            yv[j] = base[g * 3 + 1];
            pz_lds[g] = base[g * 3 + 2];
            dist[c * 2 + j] = 1e10f;
        }
        // Cache chunk 14 fully, chunk 15 for tid<992 (rows <= 4031; the
        // aliased slot region at rows 4032+ is never touched here).
        if (c == 14 || (c == 15 && tid < 992)) {
            const int r0 = (c - 14) * 2048 + 2 * tid;
            xc_lds[r0 + 0] = xv[0]; xc_lds[r0 + 1] = xv[1];
            yc_lds[r0 + 0] = yv[0]; yc_lds[r0 + 1] = yv[1];
        }
    }
    if (tid == 0) {
        s_val[0] = 0u; s_val[1] = 0u; s_val[2] = 0u;
        s_idx[0] = 0x7fffffff; s_idx[1] = 0x7fffffff; s_idx[2] = 0x7fffffff;
    }
    __syncthreads();                       // LDS + slots ready

    int w = 1;   // RAN=False seed
    int p = 0;   // rotating slot index k%3

    for (int k = 0; k < NPOINT; ++k) {
        // Centroid: xy from ws (L2, same addr -> broadcast), z from LDS.
        const float2 cxy = xy[w];
        const float cz = pz_lds[w];
        const float cx = cxy.x, cy = cxy.y;
        if (tid == 0) {
            out_idx[(size_t)b * NPOINT + k] = (float)w;
            float* o = out_xyz + ((size_t)b * NPOINT + k) * 3;
            o[0] = cx; o[1] = cy; o[2] = cz;
        }

        // Distance update; VALUE-only tracking (fmax chain).
        float best = -1.0f;
#pragma unroll
        for (int c = 0; c < NCH; ++c) {
            float4 v;
            if (c < 14) {
                v = xy4[c * 1024 + tid];               // L2 stream
            } else if (c == 14) {                      // LDS, conflict-free
                const float2 xx = *(const float2*)&xc_lds[2 * tid];
                const float2 yy = *(const float2*)&yc_lds[2 * tid];
                v = make_float4(xx.x, yy.x, xx.y, yy.y);
            } else {                                   // c == 15
                if (tid < 992) {
                    const float2 xx = *(const float2*)&xc_lds[2048 + 2 * tid];
                    const float2 yy = *(const float2*)&yc_lds[2048 + 2 * tid];
                    v = make_float4(xx.x, yy.x, xx.y, yy.y);
                } else {
                    v = xy4[15 * 1024 + tid];
                }
            }
            const float2 zz = *(const float2*)&pz_lds[c * 2048 + 2 * tid];
            {   // j = 0
                const float dx = v.x - cx;
                const float dy = v.y - cy;
                const float dz = zz.x - cz;
                const float d  = fmaf(dz, dz, fmaf(dx, dx, dy * dy));
                const float nd = fminf(dist[c * 2 + 0], d);
                dist[c * 2 + 0] = nd;
                best = fmaxf(best, nd);
            }
            {   // j = 1
                const float dx = v.z - cx;
                const float dy = v.w - cy;
                const float dz = zz.y - cz;
                const float d  = fmaf(dz, dz, fmaf(dx, dx, dy * dy));
                const float nd = fminf(dist[c * 2 + 1], d);
                dist[c * 2 + 1] = nd;
                best = fmaxf(best, nd);
            }
        }

        // Phase A: value-only wave max via DPP; lane 63 publishes.
        const float m = wave_max_dpp(best);
        if ((tid & 63) == 63)
            atomicMax(&s_val[p], __float_as_uint(m));
        __syncthreads();                   // B1: block max known
        const float M = __uint_as_float(s_val[p]);

        // Phase B (rare, exec-masked): candidates rescan dist[] for the
        // FIRST ==M (constant indices only) and publish the global index.
        if (best == M) {
            int li = 63;
#pragma unroll
            for (int i = 31; i >= 0; --i)
                if (dist[i] == M) li = i;          // ends at smallest i
            const int bi = (li >> 1) * 2048 + 2 * tid + (li & 1);
            atomicMin(&s_idx[p], bi);
        }
        __syncthreads();                   // B2: winning index known
        w = s_idx[p];
        // Reset slot for step k+2 (barriers of step k+1 order this write
        // before that slot's next atomics; its readers finished at k-1).
        const int pn2 = (p >= 1) ? (p - 1) : 2;   // (k+2)%3
        if (tid == 0) { s_val[pn2] = 0u; s_idx[pn2] = 0x7fffffff; }
        p = (p == 2) ? 0 : (p + 1);
    }
}

// ---------- fallback (register xy): used only if ws too small ----------
__global__ __launch_bounds__(NT, 1)
__attribute__((amdgpu_num_vgpr(128)))
void fps_fallback(
    const float* __restrict__ xyz, float* __restrict__ out_idx,
    float* __restrict__ out_xyz)
{
#pragma clang fp contract(off)
    __shared__ float pz_lds[NPTS];
    __shared__ unsigned int s_val[3];
    __shared__ int s_idx[3];
    const int b = blockIdx.x, tid = threadIdx.x;
    const float* base = xyz + (size_t)b * NPTS * 3;
    float px[NCH * 2], py[NCH * 2], dist[NCH * 2];
#pragma unroll
    for (int c = 0; c < NCH; ++c)
#pragma unroll
        for (int j = 0; j < 2; ++j) {
            const int i = c * 2 + j, g = c * 2048 + 2 * tid + j;
            px[i] = base[g * 3 + 0]; py[i] = base[g * 3 + 1];
            pz_lds[g] = base[g * 3 + 2]; dist[i] = 1e10f;
        }
    if (tid == 0) {
        s_val[0] = 0u; s_val[1] = 0u; s_val[2] = 0u;
        s_idx[0] = 0x7fffffff; s_idx[1] = 0x7fffffff; s_idx[2] = 0x7fffffff;
    }
    __syncthreads();
    int w = 1, p = 0;
    for (int k = 0; k < NPOINT; ++k) {
        const float cx = base[w * 3 + 0], cy = base[w * 3 + 1],
                    cz = base[w * 3 + 2];
        if (tid == 0) {
            out_idx[(size_t)b * NPOINT + k] = (float)w;
            float* o = out_xyz + ((size_t)b * NPOINT + k) * 3;
            o[0] = cx; o[1] = cy; o[2] = cz;
        }
        float best = -1.0f; int lc = 63;
#pragma unroll
        for (int c = 0; c < NCH; ++c) {
            const float2 zz = *(const float2*)&pz_lds[c * 2048 + 2 * tid];
            const float pzv[2] = { zz.x, zz.y };
#pragma unroll
            for (int j = 0; j < 2; ++j) {
                const int i = c * 2 + j;
                const float dx = px[i] - cx, dy = py[i] - cy,
                            dz = pzv[j] - cz;
                const float d  = fmaf(dz, dz, fmaf(dx, dx, dy * dy));
                const float nd = fminf(dist[i], d);
                dist[i] = nd;
                if (nd > best) { best = nd; lc = 2 * c + j; }
            }
        }
        const float m = wave_max_dpp(best);
        if ((tid & 63) == 63) atomicMax(&s_val[p], __float_as_uint(m));
        __syncthreads();
        const float M = __uint_as_float(s_val[p]);
        if (best == M) {
            const int bi = (lc >> 1) * 2048 + 2 * tid + (lc & 1);
            atomicMin(&s_idx[p], bi);
        }
        __syncthreads();
        w = s_idx[p];
        const int pn2 = (p >= 1) ? (p - 1) : 2;
        if (tid == 0) { s_val[pn2] = 0u; s_idx[pn2] = 0x7fffffff; }
        p = (p == 2) ? 0 : (p + 1);
    }
}

extern "C" void kernel_launch(void* const* d_in, const int* in_sizes, int n_in,
                              void* d_out, int out_size, void* d_ws, size_t ws_size,
                              hipStream_t stream) {
    const float* xyz = (const float*)d_in[0];
    float* out = (float*)d_out;
    float* out_idx = out;                              // B*NPOINT floats
    float* out_xyz = out + (size_t)BATCH * NPOINT;     // B*NPOINT*3 floats

    if (ws_size >= WS_NEEDED) {
        float2* wsxy = (float2*)d_ws;
        pack_xy<<<(BATCH * NPTS) / 256, 256, 0, stream>>>(xyz, wsxy);
        fps_kernel<<<BATCH, NT, 0, stream>>>(xyz, wsxy, out_idx, out_xyz);
    } else {
        fps_fallback<<<BATCH, NT, 0, stream>>>(xyz, out_idx, out_xyz);
    }
}

// Round 31
// 8055.441 us; speedup vs baseline: 1.2430x; 1.2430x over previous
//
#include <hip/hip_runtime.h>

// Farthest point sampling, B=32, N=32768, npoint=4096.
// R31 = R26 VERBATIM (proven 8.06ms champion; R27-R30 alternatives all
// regressed). Structure: 1 block/batch; dist[32] in arch VGPRs (fits the
// 64-reg class natively, VGPR=60); xy streamed from L2 ws (256KB/step,
// the measured bound: ~4680cyc of the 4830cyc step); z in 128KB static
// LDS; value-only inner loop; DPP wave max (lane63) -> 32-bit LDS
// atomicMax -> B1 -> phase-B constant-index rescan (candidates only) ->
// atomicMin -> B2 -> 3-slot rotation reset; centroid xy from ws (L2
// broadcast), z from LDS; ws xy pack kernel.
// First-occurrence argmax preserved (descending rescan ends at smallest
// i; min across candidates = numpy argmax). PASSING arithmetic (R6,
// bit-exact): d = fmaf(dz,dz, fmaf(dx,dx, dy*dy)), contract(off), fminf.
// Output float32: [B*NPOINT] idx, [B*NPOINT*3] coords.

#define BATCH  32
#define NPTS   32768
#define NPOINT 4096
#define NT     1024
#define NCH    16            // chunks of 2: 32 points per thread
#define WS_NEEDED ((size_t)BATCH * NPTS * 8)   // float2 xy per point = 8MB

#define DPP1(x, ctrl, rm) __builtin_amdgcn_update_dpp((x), (x), (ctrl), (rm), 0xf, false)

__device__ __forceinline__ float wave_max_dpp(float v) {
    unsigned int u = __float_as_uint(v);
    u = __float_as_uint(fmaxf(__uint_as_float(u), __uint_as_float(DPP1(u, 0xB1, 0xf))));
    u = __float_as_uint(fmaxf(__uint_as_float(u), __uint_as_float(DPP1(u, 0x4E, 0xf))));
    u = __float_as_uint(fmaxf(__uint_as_float(u), __uint_as_float(DPP1(u, 0x141, 0xf))));
    u = __float_as_uint(fmaxf(__uint_as_float(u), __uint_as_float(DPP1(u, 0x140, 0xf))));
    u = __float_as_uint(fmaxf(__uint_as_float(u), __uint_as_float(DPP1(u, 0x142, 0xa))));
    u = __float_as_uint(fmaxf(__uint_as_float(u), __uint_as_float(DPP1(u, 0x143, 0xc))));
    return __uint_as_float(u);   // lane 63 = wave max
}

// ---- prep: pack xy as float2[B][N] into ws (one-time, ~10us) ----
__global__ __launch_bounds__(256) void pack_xy(
    const float* __restrict__ xyz, float2* __restrict__ ws)
{
    const int i = blockIdx.x * 256 + threadIdx.x;   // 0 .. B*N-1
    ws[i] = make_float2(xyz[(size_t)i * 3 + 0], xyz[(size_t)i * 3 + 1]);
}

__global__ __launch_bounds__(NT, 1) void fps_kernel(
    const float* __restrict__ xyz,    // [B, N, 3] (setup only)
    const float2* __restrict__ wsxy,  // [B, N] packed xy
    float* __restrict__ out_idx,      // [B, NPOINT]
    float* __restrict__ out_xyz)      // [B, NPOINT, 3]
{
#pragma clang fp contract(off)
    __shared__ float pz_lds[NPTS];               // 128 KB static
    __shared__ unsigned int s_val[3];            // dist bits (>=0, monotone)
    __shared__ int s_idx[3];                     // winning global index

    const int b   = blockIdx.x;
    const int tid = threadIdx.x;
    const float* base = xyz + (size_t)b * NPTS * 3;
    const float2* xy  = wsxy + (size_t)b * NPTS;
    const float4* xy4 = (const float4*)xy;       // 2 points per float4

    float dist[NCH * 2];
#pragma unroll
    for (int c = 0; c < NCH; ++c) {
#pragma unroll
        for (int j = 0; j < 2; ++j) {
            const int g = c * 2048 + 2 * tid + j;
            pz_lds[g] = base[g * 3 + 2];
            dist[c * 2 + j] = 1e10f;
        }
    }
    if (tid == 0) {
        s_val[0] = 0u; s_val[1] = 0u; s_val[2] = 0u;
        s_idx[0] = 0x7fffffff; s_idx[1] = 0x7fffffff; s_idx[2] = 0x7fffffff;
    }
    __syncthreads();                       // pz_lds + slots ready

    int w = 1;   // RAN=False seed
    int p = 0;   // rotating slot index k%3

    for (int k = 0; k < NPOINT; ++k) {
        // Centroid: xy from ws (L2, same addr -> broadcast), z from LDS.
        const float2 cxy = xy[w];
        const float cz = pz_lds[w];
        const float cx = cxy.x, cy = cxy.y;
        if (tid == 0) {
            out_idx[(size_t)b * NPOINT + k] = (float)w;
            float* o = out_xyz + ((size_t)b * NPOINT + k) * 3;
            o[0] = cx; o[1] = cy; o[2] = cz;
        }

        // Distance update; VALUE-only tracking (fmax chain).
        float best = -1.0f;
#pragma unroll
        for (int c = 0; c < NCH; ++c) {
            const float4 v  = xy4[c * 1024 + tid];   // x0 y0 x1 y1 (L2)
            const float2 zz = *(const float2*)&pz_lds[c * 2048 + 2 * tid];
            {   // j = 0
                const float dx = v.x - cx;
                const float dy = v.y - cy;
                const float dz = zz.x - cz;
                const float d  = fmaf(dz, dz, fmaf(dx, dx, dy * dy));
                const float nd = fminf(dist[c * 2 + 0], d);
                dist[c * 2 + 0] = nd;
                best = fmaxf(best, nd);
            }
            {   // j = 1
                const float dx = v.z - cx;
                const float dy = v.w - cy;
                const float dz = zz.y - cz;
                const float d  = fmaf(dz, dz, fmaf(dx, dx, dy * dy));
                const float nd = fminf(dist[c * 2 + 1], d);
                dist[c * 2 + 1] = nd;
                best = fmaxf(best, nd);
            }
        }

        // Phase A: value-only wave max via DPP; lane 63 publishes.
        const float m = wave_max_dpp(best);
        if ((tid & 63) == 63)
            atomicMax(&s_val[p], __float_as_uint(m));
        __syncthreads();                   // B1: block max known
        const float M = __uint_as_float(s_val[p]);

        // Phase B (rare, exec-masked): candidates rescan dist[] for the
        // FIRST ==M (constant indices only) and publish the global index.
        if (best == M) {
            int li = 63;
#pragma unroll
            for (int i = 31; i >= 0; --i)
                if (dist[i] == M) li = i;          // ends at smallest i
            const int bi = (li >> 1) * 2048 + 2 * tid + (li & 1);
            atomicMin(&s_idx[p], bi);
        }
        __syncthreads();                   // B2: winning index known
        w = s_idx[p];
        // Reset slot for step k+2 (barriers of step k+1 order this write
        // before that slot's next atomics; its readers finished at k-1).
        const int pn2 = (p >= 1) ? (p - 1) : 2;   // (k+2)%3
        if (tid == 0) { s_val[pn2] = 0u; s_idx[pn2] = 0x7fffffff; }
        p = (p == 2) ? 0 : (p + 1);
    }
}

// ---------- fallback (register xy): used only if ws too small ----------
__global__ __launch_bounds__(NT, 1)
__attribute__((amdgpu_num_vgpr(128)))
void fps_fallback(
    const float* __restrict__ xyz, float* __restrict__ out_idx,
    float* __restrict__ out_xyz)
{
#pragma clang fp contract(off)
    __shared__ float pz_lds[NPTS];
    __shared__ unsigned int s_val[3];
    __shared__ int s_idx[3];
    const int b = blockIdx.x, tid = threadIdx.x;
    const float* base = xyz + (size_t)b * NPTS * 3;
    float px[NCH * 2], py[NCH * 2], dist[NCH * 2];
#pragma unroll
    for (int c = 0; c < NCH; ++c)
#pragma unroll
        for (int j = 0; j < 2; ++j) {
            const int i = c * 2 + j, g = c * 2048 + 2 * tid + j;
            px[i] = base[g * 3 + 0]; py[i] = base[g * 3 + 1];
            pz_lds[g] = base[g * 3 + 2]; dist[i] = 1e10f;
        }
    if (tid == 0) {
        s_val[0] = 0u; s_val[1] = 0u; s_val[2] = 0u;
        s_idx[0] = 0x7fffffff; s_idx[1] = 0x7fffffff; s_idx[2] = 0x7fffffff;
    }
    __syncthreads();
    int w = 1, p = 0;
    for (int k = 0; k < NPOINT; ++k) {
        const float cx = base[w * 3 + 0], cy = base[w * 3 + 1],
                    cz = base[w * 3 + 2];
        if (tid == 0) {
            out_idx[(size_t)b * NPOINT + k] = (float)w;
            float* o = out_xyz + ((size_t)b * NPOINT + k) * 3;
            o[0] = cx; o[1] = cy; o[2] = cz;
        }
        float best = -1.0f; int lc = 63;
#pragma unroll
        for (int c = 0; c < NCH; ++c) {
            const float2 zz = *(const float2*)&pz_lds[c * 2048 + 2 * tid];
            const float pzv[2] = { zz.x, zz.y };
#pragma unroll
            for (int j = 0; j < 2; ++j) {
                const int i = c * 2 + j;
                const float dx = px[i] - cx, dy = py[i] - cy,
                            dz = pzv[j] - cz;
                const float d  = fmaf(dz, dz, fmaf(dx, dx, dy * dy));
                const float nd = fminf(dist[i], d);
                dist[i] = nd;
                if (nd > best) { best = nd; lc = 2 * c + j; }
            }
        }
        const float m = wave_max_dpp(best);
        if ((tid & 63) == 63) atomicMax(&s_val[p], __float_as_uint(m));
        __syncthreads();
        const float M = __uint_as_float(s_val[p]);
        if (best == M) {
            const int bi = (lc >> 1) * 2048 + 2 * tid + (lc & 1);
            atomicMin(&s_idx[p], bi);
        }
        __syncthreads();
        w = s_idx[p];
        const int pn2 = (p >= 1) ? (p - 1) : 2;
        if (tid == 0) { s_val[pn2] = 0u; s_idx[pn2] = 0x7fffffff; }
        p = (p == 2) ? 0 : (p + 1);
    }
}

extern "C" void kernel_launch(void* const* d_in, const int* in_sizes, int n_in,
                              void* d_out, int out_size, void* d_ws, size_t ws_size,
                              hipStream_t stream) {
    const float* xyz = (const float*)d_in[0];
    float* out = (float*)d_out;
    float* out_idx = out;                              // B*NPOINT floats
    float* out_xyz = out + (size_t)BATCH * NPOINT;     // B*NPOINT*3 floats

    if (ws_size >= WS_NEEDED) {
        float2* wsxy = (float2*)d_ws;
        pack_xy<<<(BATCH * NPTS) / 256, 256, 0, stream>>>(xyz, wsxy);
        fps_kernel<<<BATCH, NT, 0, stream>>>(xyz, wsxy, out_idx, out_xyz);
    } else {
        fps_fallback<<<BATCH, NT, 0, stream>>>(xyz, out_idx, out_xyz);
    }
}